// Round 4
// baseline (667.346 us; speedup 1.0000x reference)
//
#include <hip/hip_runtime.h>

#define HW  262144     // 512*512
#define HW4 65536      // HW/4
#define NPATCH 16384   // 16 * 32 * 32

// ws layout (floats):
// [0]                : exposure sum of (patch_mean - E)^2
// [1]                : tv vertical sum
// [2]                : tv horizontal sum
// [3 .. 51)          : color channel sums, index 3 + b*3 + c   (48)
// [51 .. 51+128*11)  : semantic stats, index 51 + (b*8+k)*11 + s
//                      s: 0=sumM 1=sumM2 2..4=sRM[c] 5..7=sRM2[c] 8..10=sR2M2[c]
#define WS_FLOATS (3 + 48 + 128*11)

// 128 groups x 13 roles {8 sem, 2 L-pair, 3 color} = 1664 blocks of 512 thr.
#define TOTAL_BLOCKS (13 * 128)

__device__ __forceinline__ float wave_reduce(float x) {
#pragma unroll
  for (int o = 32; o >= 1; o >>= 1) x += __shfl_down(x, o);
  return x;
}

// one element update, single k: 11 named scalar accumulators in scope
#define CEL(x0v, x1v, x2v, mmv)                                                \
  {                                                                            \
    float _m = (mmv), _m2 = _m * _m;                                           \
    float _x0 = (x0v), _x1 = (x1v), _x2 = (x2v);                               \
    an += _m;  an2 += _m2;                                                     \
    ap0 += _x0 * _m;  ap1 += _x1 * _m;  ap2 += _x2 * _m;                       \
    aq0 += _x0 * _m2; aq1 += _x1 * _m2; aq2 += _x2 * _m2;                      \
    ar0 += _x0 * _x0 * _m2; ar1 += _x1 * _x1 * _m2; ar2 += _x2 * _x2 * _m2;    \
  }

#define CONSUME(G0, G1, G2, GM)                                                \
  CEL(G0.x, G1.x, G2.x, GM.x)                                                  \
  CEL(G0.y, G1.y, G2.y, GM.y)                                                  \
  CEL(G0.z, G1.z, G2.z, GM.z)                                                  \
  CEL(G0.w, G1.w, G2.w, GM.w)

__global__ __launch_bounds__(512, 8) void mega_kernel(
    const float* __restrict__ L, const float* __restrict__ R,
    const float* __restrict__ I, const float* __restrict__ M,
    float* __restrict__ ws) {
  const int bid = blockIdx.x;
  const int tid = threadIdx.x;
  const int lane = tid & 63;
  const int grp = bid / 13;
  const int role = bid - grp * 13;

  if (role < 8) {
    // ------------- semantic stats: R (B,3,H,W) x M (B,8,H,W) ---------------
    // Block = 8 waves = 8 k's over the same pixel slice (R re-reads hit L1).
    // Per wave: 1 k, 11 accumulators, register-rotated 2-deep load pipeline,
    // chunk phase staggered by wave to decorrelate streams.
    const int sidx = grp * 8 + role;   // 0..1023
    const int b = sidx >> 6;           // 0..15
    const int xb = sidx & 63;          // 0..63
    const int wv = tid >> 6;           // 0..7 == k
    const float4* R4 = (const float4*)(R + (size_t)b * 3 * HW);
    const float4* M4 = (const float4*)(M + ((size_t)b * 8 + wv) * HW);
    const int base = xb * 1024 + lane; // f4 index; chunks at +c*64, c in [0,16)

    float an = 0.f, an2 = 0.f, ap0 = 0.f, ap1 = 0.f, ap2 = 0.f;
    float aq0 = 0.f, aq1 = 0.f, aq2 = 0.f, ar0 = 0.f, ar1 = 0.f, ar2 = 0.f;

    const int ph = wv * 2;
    int c0 = ph & 15;
    int ia = base + c0 * 64;
    float4 Ar0 = R4[ia], Ar1 = R4[ia + HW4], Ar2 = R4[ia + 2 * HW4];
    float4 Am = M4[ia];
#pragma unroll
    for (int it = 0; it < 16; it += 2) {
      // prefetch B (it+1) while A is in regs
      int cb = (it + 1 + ph) & 15;
      int ib = base + cb * 64;
      float4 Br0 = R4[ib], Br1 = R4[ib + HW4], Br2 = R4[ib + 2 * HW4];
      float4 Bm = M4[ib];
      CONSUME(Ar0, Ar1, Ar2, Am)
      if (it < 14) {  // prefetch next A (it+2) while B is in regs
        int ca = (it + 2 + ph) & 15;
        int ia2 = base + ca * 64;
        Ar0 = R4[ia2]; Ar1 = R4[ia2 + HW4]; Ar2 = R4[ia2 + 2 * HW4];
        Am = M4[ia2];
      }
      CONSUME(Br0, Br1, Br2, Bm)
    }

    float* dst = ws + 51 + (size_t)((b * 8 + wv) * 11);
    float v;
    v = wave_reduce(an);  if (lane == 0) atomicAdd(&dst[0], v);
    v = wave_reduce(an2); if (lane == 0) atomicAdd(&dst[1], v);
    v = wave_reduce(ap0); if (lane == 0) atomicAdd(&dst[2], v);
    v = wave_reduce(ap1); if (lane == 0) atomicAdd(&dst[3], v);
    v = wave_reduce(ap2); if (lane == 0) atomicAdd(&dst[4], v);
    v = wave_reduce(aq0); if (lane == 0) atomicAdd(&dst[5], v);
    v = wave_reduce(aq1); if (lane == 0) atomicAdd(&dst[6], v);
    v = wave_reduce(aq2); if (lane == 0) atomicAdd(&dst[7], v);
    v = wave_reduce(ar0); if (lane == 0) atomicAdd(&dst[8], v);
    v = wave_reduce(ar1); if (lane == 0) atomicAdd(&dst[9], v);
    v = wave_reduce(ar2); if (lane == 0) atomicAdd(&dst[10], v);
    return;
  }

  if (role < 10) {
    // ------------- L bands: TV (v+h) + exposure; 2 bands per block ---------
    const int lidx = grp * 2 + (role - 8);  // 0..255
    const int sub = tid >> 8;               // 0/1 -> band
    const int stid = tid & 255;
    const int band = lidx * 2 + sub;        // 0..511
    const int b = band >> 5;                // 0..15
    const int pr = band & 31;               // patch row
    const int half = stid >> 7;             // 0..1
    const int c4 = stid & 127;              // f4 column
    const int row0 = pr * 16 + half * 8;
    const float* Lb = L + (size_t)b * HW;
    const float4* L4b = (const float4*)Lb;
    __shared__ float part[2][2][128];
    __shared__ float redv[2][4], redh[2][4];

    float sv = 0.f, sh = 0.f, ps = 0.f;
    float4 cur = L4b[row0 * 128 + c4];
#pragma unroll
    for (int r = 0; r < 8; ++r) {
      sh += fabsf(cur.x - cur.y) + fabsf(cur.y - cur.z) + fabsf(cur.z - cur.w);
      float nx = __shfl_down(cur.x, 1);  // next f4's .x, same row
      if (lane == 63 && c4 < 127) nx = Lb[(row0 + r) * 512 + c4 * 4 + 4];
      if (c4 < 127) sh += fabsf(cur.w - nx);
      ps += (cur.x + cur.y) + (cur.z + cur.w);
      int nr = row0 + r + 1;
      if (nr < 512) {
        float4 nxt = L4b[nr * 128 + c4];
        sv += fabsf(cur.x - nxt.x) + fabsf(cur.y - nxt.y) +
              fabsf(cur.z - nxt.z) + fabsf(cur.w - nxt.w);
        cur = nxt;
      }
    }
    part[sub][half][c4] = ps;
    sv = wave_reduce(sv);
    sh = wave_reduce(sh);
    int wv2 = stid >> 6;  // wave within sub-block: 0..3
    if (lane == 0) { redv[sub][wv2] = sv; redh[sub][wv2] = sh; }
    __syncthreads();
    if (stid == 0) {
      atomicAdd(&ws[1], (redv[sub][0] + redv[sub][1]) + (redv[sub][2] + redv[sub][3]));
      atomicAdd(&ws[2], (redh[sub][0] + redh[sub][1]) + (redh[sub][2] + redh[sub][3]));
    }
    float e = 0.f;
    if (stid < 32) {  // patch p = stid covers f4 cols [4p, 4p+4)
      float s = 0.f;
#pragma unroll
      for (int h = 0; h < 2; ++h)
#pragma unroll
        for (int q = 0; q < 4; ++q) s += part[sub][h][stid * 4 + q];
      float d = s * (1.0f / 256.0f) - 0.6f;
      e = d * d;
    }
    e = wave_reduce(e);
    if (stid == 0) atomicAdd(&ws[0], e);
    return;
  }

  {
    // ------------- color: per (b,c) channel sums of I_enh ------------------
    const int cid = grp * 3 + (role - 10);  // 0..383
    const int slice = cid >> 3;             // 0..47
    const int xb8 = cid & 7;
    const float4* I4 = (const float4*)(I + (size_t)slice * HW);
    float s = 0.f;
    int i = xb8 * 8192 + tid;
#pragma unroll 4
    for (int it = 0; it < 16; ++it, i += 512) {
      float4 v = I4[i];
      s += (v.x + v.y) + (v.z + v.w);
    }
    s = wave_reduce(s);
    __shared__ float red[8];
    int wv = tid >> 6;
    if (lane == 0) red[wv] = s;
    __syncthreads();
    if (tid == 0) {
      float t = ((red[0] + red[1]) + (red[2] + red[3])) +
                ((red[4] + red[5]) + (red[6] + red[7]));
      atomicAdd(&ws[3 + slice], t);
    }
  }
}

// ---------------- final combine ----------------
__global__ __launch_bounds__(256) void final_kernel(const float* __restrict__ ws,
                                                    float* __restrict__ out) {
  __shared__ float red[256];
  int t = threadIdx.x;
  float sem = 0.f;
  if (t < 128) {
    const float* s = ws + 51 + t * 11;
    float n = s[0] + 1e-6f;
    float v = 0.f;
#pragma unroll
    for (int c = 0; c < 3; ++c) {
      float mean = s[2 + c] / n;
      v += s[8 + c] - 2.0f * mean * s[5 + c] + mean * mean * s[1];
    }
    sem = v / n;
  }
  red[t] = sem;
  __syncthreads();
  for (int s = 128; s > 0; s >>= 1) {
    if (t < s) red[t] += red[t + s];
    __syncthreads();
  }
  if (t == 0) {
    float L_sem = red[0] / 16.0f;
    float L_exp = ws[0] / (float)NPATCH;
    float L_tv = ws[1] / (16.0f * 511.0f * 512.0f) +
                 ws[2] / (16.0f * 512.0f * 511.0f);
    float L_color = 0.f;
#pragma unroll
    for (int b = 0; b < 16; ++b) {
      float r = ws[3 + b * 3 + 0] * (1.0f / (float)HW);
      float g = ws[3 + b * 3 + 1] * (1.0f / (float)HW);
      float bl = ws[3 + b * 3 + 2] * (1.0f / (float)HW);
      L_color += (r - g) * (r - g) + (r - bl) * (r - bl) + (g - bl) * (g - bl);
    }
    L_color *= (1.0f / 16.0f);
    out[0] = 10.0f * L_exp + 1.0f * L_tv + 10.0f * L_color + 50.0f * L_sem;
  }
}

extern "C" void kernel_launch(void* const* d_in, const int* in_sizes, int n_in,
                              void* d_out, int out_size, void* d_ws, size_t ws_size,
                              hipStream_t stream) {
  const float* L     = (const float*)d_in[0];  // (16,1,512,512)
  const float* R     = (const float*)d_in[1];  // (16,3,512,512)
  const float* I_enh = (const float*)d_in[2];  // (16,3,512,512)
  const float* M     = (const float*)d_in[3];  // (16,8,512,512)
  float* out = (float*)d_out;
  float* ws  = (float*)d_ws;

  hipMemsetAsync(d_ws, 0, WS_FLOATS * sizeof(float), stream);
  mega_kernel<<<TOTAL_BLOCKS, 512, 0, stream>>>(L, R, I_enh, M, ws);
  final_kernel<<<1, 256, 0, stream>>>(ws, out);
}

// Round 6
// 144.889 us; speedup vs baseline: 4.6059x; 4.6059x over previous
//
#include <hip/hip_runtime.h>

#define HW  262144     // 512*512
#define HW4 65536      // HW/4
#define NPATCH 16384   // 16 * 32 * 32

// ws layout (floats):
// [0]                : exposure sum of (patch_mean - E)^2
// [1]                : tv vertical sum
// [2]                : tv horizontal sum
// [3 .. 51)          : color channel sums, index 3 + b*3 + c   (48)
// [51 .. 51+128*11)  : semantic stats, index 51 + (b*8+k)*11 + s
//                      s: 0=sumM 1=sumM2 2..4=sRM[c] 5..7=sRM2[c] 8..10=sR2M2[c]
#define WS_FLOATS (3 + 48 + 128*11)

#define SEM_BLOCKS   1024   // 16 images x 64 windows, 512 thr (8 waves = 8 k)
#define LBAND_BLOCKS 256    // 2 bands per block
#define COLOR_BLOCKS 384
#define TOTAL_BLOCKS (SEM_BLOCKS + LBAND_BLOCKS + COLOR_BLOCKS)

typedef float nfloat4 __attribute__((ext_vector_type(4)));

__device__ __forceinline__ float wave_reduce(float x) {
#pragma unroll
  for (int o = 32; o >= 1; o >>= 1) x += __shfl_down(x, o);
  return x;
}

// non-temporal float4 load (native vector type required by the builtin)
__device__ __forceinline__ float4 ntload4(const float4* p) {
  nfloat4 v = __builtin_nontemporal_load((const nfloat4*)p);
  return make_float4(v.x, v.y, v.z, v.w);
}

// one element update, single k; t-form: t=x*m -> p+=t, q+=t*m, r+=t*t
#define CEL(x0v, x1v, x2v, mmv)                                                \
  {                                                                            \
    float _m = (mmv), _m2 = _m * _m;                                           \
    float _t0 = (x0v) * _m, _t1 = (x1v) * _m, _t2 = (x2v) * _m;                \
    an += _m;  an2 += _m2;                                                     \
    ap0 += _t0;  ap1 += _t1;  ap2 += _t2;                                      \
    aq0 += _t0 * _m; aq1 += _t1 * _m; aq2 += _t2 * _m;                         \
    ar0 += _t0 * _t0; ar1 += _t1 * _t1; ar2 += _t2 * _t2;                      \
  }

#define CONSUME(G0, G1, G2, GM)                                                \
  CEL(G0.x, G1.x, G2.x, GM.x)                                                  \
  CEL(G0.y, G1.y, G2.y, GM.y)                                                  \
  CEL(G0.z, G1.z, G2.z, GM.z)                                                  \
  CEL(G0.w, G1.w, G2.w, GM.w)

__global__ __launch_bounds__(512) void mega_kernel(
    const float* __restrict__ L, const float* __restrict__ R,
    const float* __restrict__ I, const float* __restrict__ M,
    float* __restrict__ ws) {
  const int bid = blockIdx.x;
  const int tid = threadIdx.x;
  const int lane = tid & 63;

  if (bid < SEM_BLOCKS) {
    // ------------- semantic stats: R (B,3,H,W) x M (B,8,H,W) ---------------
    // 8 waves = 8 k's over the SAME 1024-f4 window: R re-reads hit L1.
    // Per wave: 11 accumulators, 2-deep register-rotated prefetch over 16
    // contiguous 1KB chunks. M (read-once, 134MB) via non-temporal loads.
    const int b = bid >> 6;            // 0..15
    const int xb = bid & 63;           // 0..63
    const int wv = tid >> 6;           // 0..7 == k
    const float4* R4 = (const float4*)(R + (size_t)b * 3 * HW);
    const float4* M4 = (const float4*)(M + ((size_t)b * 8 + wv) * HW);
    const int base = xb * 1024 + lane; // f4 index; chunks at +c*64, c in [0,16)

    float an = 0.f, an2 = 0.f, ap0 = 0.f, ap1 = 0.f, ap2 = 0.f;
    float aq0 = 0.f, aq1 = 0.f, aq2 = 0.f, ar0 = 0.f, ar1 = 0.f, ar2 = 0.f;

    float4 Ar0 = R4[base], Ar1 = R4[base + HW4], Ar2 = R4[base + 2 * HW4];
    float4 Am = ntload4(&M4[base]);
#pragma unroll
    for (int it = 0; it < 16; ++it) {
      float4 Br0, Br1, Br2, Bm;
      if (it < 15) {  // prefetch next chunk while current is consumed
        int j = base + (it + 1) * 64;
        Br0 = R4[j]; Br1 = R4[j + HW4]; Br2 = R4[j + 2 * HW4];
        Bm = ntload4(&M4[j]);
      }
      CONSUME(Ar0, Ar1, Ar2, Am)
      if (it < 15) { Ar0 = Br0; Ar1 = Br1; Ar2 = Br2; Am = Bm; }
    }

    float* dst = ws + 51 + (size_t)((b * 8 + wv) * 11);
    float v;
    v = wave_reduce(an);  if (lane == 0) atomicAdd(&dst[0], v);
    v = wave_reduce(an2); if (lane == 0) atomicAdd(&dst[1], v);
    v = wave_reduce(ap0); if (lane == 0) atomicAdd(&dst[2], v);
    v = wave_reduce(ap1); if (lane == 0) atomicAdd(&dst[3], v);
    v = wave_reduce(ap2); if (lane == 0) atomicAdd(&dst[4], v);
    v = wave_reduce(aq0); if (lane == 0) atomicAdd(&dst[5], v);
    v = wave_reduce(aq1); if (lane == 0) atomicAdd(&dst[6], v);
    v = wave_reduce(aq2); if (lane == 0) atomicAdd(&dst[7], v);
    v = wave_reduce(ar0); if (lane == 0) atomicAdd(&dst[8], v);
    v = wave_reduce(ar1); if (lane == 0) atomicAdd(&dst[9], v);
    v = wave_reduce(ar2); if (lane == 0) atomicAdd(&dst[10], v);
    return;
  }

  if (bid < SEM_BLOCKS + LBAND_BLOCKS) {
    // ------------- L bands: TV (v+h) + exposure; 2 bands per block ---------
    const int lidx = bid - SEM_BLOCKS;      // 0..255
    const int sub = tid >> 8;               // 0/1 -> band
    const int stid = tid & 255;
    const int band = lidx * 2 + sub;        // 0..511
    const int b = band >> 5;                // 0..15
    const int pr = band & 31;               // patch row
    const int half = stid >> 7;             // 0..1
    const int c4 = stid & 127;              // f4 column
    const int row0 = pr * 16 + half * 8;
    const float* Lb = L + (size_t)b * HW;
    const float4* L4b = (const float4*)Lb;
    __shared__ float part[2][2][128];
    __shared__ float redv[2][4], redh[2][4];

    float sv = 0.f, sh = 0.f, ps = 0.f;
    float4 cur = L4b[row0 * 128 + c4];
#pragma unroll
    for (int r = 0; r < 8; ++r) {
      sh += fabsf(cur.x - cur.y) + fabsf(cur.y - cur.z) + fabsf(cur.z - cur.w);
      float nx = __shfl_down(cur.x, 1);  // next f4's .x, same row
      if (lane == 63 && c4 < 127) nx = Lb[(row0 + r) * 512 + c4 * 4 + 4];
      if (c4 < 127) sh += fabsf(cur.w - nx);
      ps += (cur.x + cur.y) + (cur.z + cur.w);
      int nr = row0 + r + 1;
      if (nr < 512) {
        float4 nxt = L4b[nr * 128 + c4];
        sv += fabsf(cur.x - nxt.x) + fabsf(cur.y - nxt.y) +
              fabsf(cur.z - nxt.z) + fabsf(cur.w - nxt.w);
        cur = nxt;
      }
    }
    part[sub][half][c4] = ps;
    sv = wave_reduce(sv);
    sh = wave_reduce(sh);
    int wv2 = stid >> 6;  // wave within sub-block: 0..3
    if (lane == 0) { redv[sub][wv2] = sv; redh[sub][wv2] = sh; }
    __syncthreads();
    if (stid == 0) {
      atomicAdd(&ws[1],
                (redv[sub][0] + redv[sub][1]) + (redv[sub][2] + redv[sub][3]));
      atomicAdd(&ws[2],
                (redh[sub][0] + redh[sub][1]) + (redh[sub][2] + redh[sub][3]));
    }
    float e = 0.f;
    if (stid < 32) {  // patch p = stid covers f4 cols [4p, 4p+4)
      float s = 0.f;
#pragma unroll
      for (int h = 0; h < 2; ++h)
#pragma unroll
        for (int q = 0; q < 4; ++q) s += part[sub][h][stid * 4 + q];
      float d = s * (1.0f / 256.0f) - 0.6f;
      e = d * d;
    }
    e = wave_reduce(e);
    if (stid == 0) atomicAdd(&ws[0], e);
    return;
  }

  {
    // ------------- color: per (b,c) channel sums of I_enh ------------------
    const int cid = bid - (SEM_BLOCKS + LBAND_BLOCKS);  // 0..383
    const int slice = cid >> 3;             // 0..47
    const int xb8 = cid & 7;
    const float4* I4 = (const float4*)(I + (size_t)slice * HW);
    float s = 0.f;
    int i = xb8 * 8192 + tid;
#pragma unroll 4
    for (int it = 0; it < 16; ++it, i += 512) {
      float4 v = I4[i];
      s += (v.x + v.y) + (v.z + v.w);
    }
    s = wave_reduce(s);
    __shared__ float red[8];
    int wv = tid >> 6;
    if (lane == 0) red[wv] = s;
    __syncthreads();
    if (tid == 0) {
      float t = ((red[0] + red[1]) + (red[2] + red[3])) +
                ((red[4] + red[5]) + (red[6] + red[7]));
      atomicAdd(&ws[3 + slice], t);
    }
  }
}

// ---------------- final combine ----------------
__global__ __launch_bounds__(256) void final_kernel(const float* __restrict__ ws,
                                                    float* __restrict__ out) {
  __shared__ float red[256];
  int t = threadIdx.x;
  float sem = 0.f;
  if (t < 128) {
    const float* s = ws + 51 + t * 11;
    float n = s[0] + 1e-6f;
    float v = 0.f;
#pragma unroll
    for (int c = 0; c < 3; ++c) {
      float mean = s[2 + c] / n;
      v += s[8 + c] - 2.0f * mean * s[5 + c] + mean * mean * s[1];
    }
    sem = v / n;
  }
  red[t] = sem;
  __syncthreads();
  for (int s = 128; s > 0; s >>= 1) {
    if (t < s) red[t] += red[t + s];
    __syncthreads();
  }
  if (t == 0) {
    float L_sem = red[0] / 16.0f;
    float L_exp = ws[0] / (float)NPATCH;
    float L_tv = ws[1] / (16.0f * 511.0f * 512.0f) +
                 ws[2] / (16.0f * 512.0f * 511.0f);
    float L_color = 0.f;
#pragma unroll
    for (int b = 0; b < 16; ++b) {
      float r = ws[3 + b * 3 + 0] * (1.0f / (float)HW);
      float g = ws[3 + b * 3 + 1] * (1.0f / (float)HW);
      float bl = ws[3 + b * 3 + 2] * (1.0f / (float)HW);
      L_color += (r - g) * (r - g) + (r - bl) * (r - bl) + (g - bl) * (g - bl);
    }
    L_color *= (1.0f / 16.0f);
    out[0] = 10.0f * L_exp + 1.0f * L_tv + 10.0f * L_color + 50.0f * L_sem;
  }
}

extern "C" void kernel_launch(void* const* d_in, const int* in_sizes, int n_in,
                              void* d_out, int out_size, void* d_ws, size_t ws_size,
                              hipStream_t stream) {
  const float* L     = (const float*)d_in[0];  // (16,1,512,512)
  const float* R     = (const float*)d_in[1];  // (16,3,512,512)
  const float* I_enh = (const float*)d_in[2];  // (16,3,512,512)
  const float* M     = (const float*)d_in[3];  // (16,8,512,512)
  float* out = (float*)d_out;
  float* ws  = (float*)d_ws;

  (void)hipMemsetAsync(d_ws, 0, WS_FLOATS * sizeof(float), stream);
  mega_kernel<<<TOTAL_BLOCKS, 512, 0, stream>>>(L, R, I_enh, M, ws);
  final_kernel<<<1, 256, 0, stream>>>(ws, out);
}